// Round 2
// baseline (83.424 us; speedup 1.0000x reference)
//
#include <hip/hip_runtime.h>

// ClusterLoss closed form (group_ids provably irrelevant):
//   F   = ||W||_F^2
//   t_d = sum_i W[d,i]
//   out = F + 0.5*(F - ||t||^2/N)/batch_size
//
// Single fused kernel: 2048 blocks (2 per row -> 32 waves/CU, full occupancy),
// last-block-done final reduction (mod-2048 counter: poison/replay safe).

#define D_ROWS 1024
#define N_CLS  50000
#define NVEC   (N_CLS / 4)      // 12500 float4 per row
#define PARTS  2
#define CHUNK  (NVEC / PARTS)   // 6250 float4 per block
#define NBLK   (D_ROWS * PARTS) // 2048 blocks

__global__ __launch_bounds__(256) void cluster_fused(
    const float* __restrict__ W,
    const int* __restrict__ bs_ptr,
    float* __restrict__ out,
    float* __restrict__ sum_part,   // [NBLK]
    float* __restrict__ sq_part,    // [NBLK]
    unsigned int* __restrict__ counter)
{
    const int b    = blockIdx.x;
    const int row  = b >> 1;
    const int part = b & 1;
    const float4* __restrict__ Wp =
        reinterpret_cast<const float4*>(W + (size_t)row * N_CLS) + part * CHUNK;

    float s = 0.0f, q = 0.0f;
    for (int i = threadIdx.x; i < CHUNK; i += 256) {
        float4 v = Wp[i];
        s += (v.x + v.y) + (v.z + v.w);
        q += v.x * v.x + v.y * v.y + v.z * v.z + v.w * v.w;
    }

    #pragma unroll
    for (int off = 32; off; off >>= 1) {
        s += __shfl_down(s, off, 64);
        q += __shfl_down(q, off, 64);
    }

    __shared__ float ss[4], sq[4];
    __shared__ bool amLast;
    const int wid  = threadIdx.x >> 6;
    const int lane = threadIdx.x & 63;
    if (lane == 0) { ss[wid] = s; sq[wid] = q; }
    __syncthreads();

    if (threadIdx.x == 0) {
        sum_part[b] = ss[0] + ss[1] + ss[2] + ss[3];
        sq_part[b]  = sq[0] + sq[1] + sq[2] + sq[3];
        __threadfence();                              // release: drain to coherent point
        unsigned int old = atomicAdd(counter, 1u);    // device-scope RMW
        amLast = ((old & (NBLK - 1)) == (NBLK - 1));  // poison/replay-invariant
    }
    __syncthreads();
    if (!amLast) return;

    __threadfence();  // acquire: invalidate stale L2 lines (cross-XCD, G16)

    float t2 = 0.0f, f = 0.0f;
    {
        volatile const float* vs = sum_part;
        volatile const float* vq = sq_part;
        for (int r = threadIdx.x; r < D_ROWS; r += 256) {
            float rs = vs[2 * r] + vs[2 * r + 1];
            t2 += rs * rs;
            f  += vq[2 * r] + vq[2 * r + 1];
        }
    }

    #pragma unroll
    for (int off = 32; off; off >>= 1) {
        t2 += __shfl_down(t2, off, 64);
        f  += __shfl_down(f, off, 64);
    }

    __shared__ float st[4], sf[4];
    if (lane == 0) { st[wid] = t2; sf[wid] = f; }
    __syncthreads();
    if (threadIdx.x == 0) {
        float T2 = st[0] + st[1] + st[2] + st[3];
        float F  = sf[0] + sf[1] + sf[2] + sf[3];
        float bs = (float)bs_ptr[0];
        out[0] = F + 0.5f * (F - T2 / (float)N_CLS) / bs;
    }
}

extern "C" void kernel_launch(void* const* d_in, const int* in_sizes, int n_in,
                              void* d_out, int out_size, void* d_ws, size_t ws_size,
                              hipStream_t stream) {
    const float* W      = (const float*)d_in[0];
    // d_in[1] = group_ids : unused (loss is invariant to grouping — see header)
    const int*   bs_ptr = (const int*)d_in[2];
    float*       out    = (float*)d_out;

    float*        sum_part = (float*)d_ws;               // NBLK floats
    float*        sq_part  = sum_part + NBLK;            // NBLK floats
    unsigned int* counter  = (unsigned int*)(sq_part + NBLK);

    cluster_fused<<<NBLK, 256, 0, stream>>>(W, bs_ptr, out, sum_part, sq_part, counter);
}

// Round 3
// 37.645 us; speedup vs baseline: 2.2161x; 2.2161x over previous
//
#include <hip/hip_runtime.h>

// ClusterLoss closed form (group_ids provably irrelevant):
//   F   = ||W||_F^2
//   t_d = sum_i W[d,i]
//   out = F + 0.5*(F - ||t||^2/N)/batch_size
//
// Two kernels, no atomics (round-2 lesson: 2048 same-address device-scope
// atomics serialize at ~73ns each -> 150us tail). Kernel 1: 2048 blocks
// (2 per row -> 8 blocks/CU -> 32 waves/CU, 100% occupancy) stream W once.
// Kernel 2: 1 block folds 2048 partials. Double accumulators (VALU ~4% busy).

#define D_ROWS 1024
#define N_CLS  50000
#define NVEC   (N_CLS / 4)      // 12500 float4 per row
#define PARTS  2
#define CHUNK  (NVEC / PARTS)   // 6250 float4 per block
#define NBLK   (D_ROWS * PARTS) // 2048

__global__ __launch_bounds__(256) void cluster_row_reduce(
    const float* __restrict__ W,
    double* __restrict__ sum_part,   // [NBLK]
    double* __restrict__ sq_part)    // [NBLK]
{
    const int b    = blockIdx.x;
    const int row  = b >> 1;
    const int part = b & 1;
    const float4* __restrict__ Wp =
        reinterpret_cast<const float4*>(W + (size_t)row * N_CLS) + part * CHUNK;

    double s = 0.0, q = 0.0;
    #pragma unroll 4
    for (int i = threadIdx.x; i < CHUNK; i += 256) {
        float4 v = Wp[i];
        s += (double)v.x + (double)v.y + (double)v.z + (double)v.w;
        q += (double)v.x * v.x + (double)v.y * v.y
           + (double)v.z * v.z + (double)v.w * v.w;
    }

    #pragma unroll
    for (int off = 32; off; off >>= 1) {
        s += __shfl_down(s, off, 64);
        q += __shfl_down(q, off, 64);
    }

    __shared__ double ss[4], sq[4];
    const int wid  = threadIdx.x >> 6;
    const int lane = threadIdx.x & 63;
    if (lane == 0) { ss[wid] = s; sq[wid] = q; }
    __syncthreads();
    if (threadIdx.x == 0) {
        sum_part[b] = ss[0] + ss[1] + ss[2] + ss[3];
        sq_part[b]  = sq[0] + sq[1] + sq[2] + sq[3];
    }
}

__global__ __launch_bounds__(256) void cluster_final_reduce(
    const double* __restrict__ sum_part,
    const double* __restrict__ sq_part,
    const int* __restrict__ bs_ptr,
    float* __restrict__ out)
{
    double t2 = 0.0, f = 0.0;
    for (int r = threadIdx.x; r < D_ROWS; r += 256) {
        double rs = sum_part[2 * r] + sum_part[2 * r + 1];
        t2 += rs * rs;
        f  += sq_part[2 * r] + sq_part[2 * r + 1];
    }

    #pragma unroll
    for (int off = 32; off; off >>= 1) {
        t2 += __shfl_down(t2, off, 64);
        f  += __shfl_down(f, off, 64);
    }

    __shared__ double st[4], sf[4];
    const int wid  = threadIdx.x >> 6;
    const int lane = threadIdx.x & 63;
    if (lane == 0) { st[wid] = t2; sf[wid] = f; }
    __syncthreads();
    if (threadIdx.x == 0) {
        double T2 = st[0] + st[1] + st[2] + st[3];
        double F  = sf[0] + sf[1] + sf[2] + sf[3];
        double bs = (double)bs_ptr[0];
        out[0] = (float)(F + 0.5 * (F - T2 / (double)N_CLS) / bs);
    }
}

extern "C" void kernel_launch(void* const* d_in, const int* in_sizes, int n_in,
                              void* d_out, int out_size, void* d_ws, size_t ws_size,
                              hipStream_t stream) {
    const float* W      = (const float*)d_in[0];
    // d_in[1] = group_ids : unused (loss is invariant to grouping — see header)
    const int*   bs_ptr = (const int*)d_in[2];
    float*       out    = (float*)d_out;

    double* sum_part = (double*)d_ws;          // NBLK doubles
    double* sq_part  = sum_part + NBLK;        // NBLK doubles

    cluster_row_reduce<<<NBLK, 256, 0, stream>>>(W, sum_part, sq_part);
    cluster_final_reduce<<<1, 256, 0, stream>>>(sum_part, sq_part, bs_ptr, out);
}

// Round 5
// 37.457 us; speedup vs baseline: 2.2272x; 1.0050x over previous
//
#include <hip/hip_runtime.h>

// ClusterLoss closed form (group_ids provably irrelevant):
//   F   = ||W||_F^2
//   t_d = sum_i W[d,i]
//   out = F + 0.5*(F - ||t||^2/N)/batch_size
//
// Two kernels, no atomics (round-2: 2048 same-address device-scope atomics +
// per-block threadfence cost ~+110us). Round-3: k1 read-BW-bound ~6.2 TB/s
// regardless of occupancy/unroll/accum width. This round: nontemporal loads
// (nt bit: evict-first — zero reuse in one pass; 204.8MB/256MB L3 churn
// otherwise) to probe for >6.3 TB/s pure-read. Native ext_vector type for the
// builtin (HIP float4 class is rejected).

#define D_ROWS 1024
#define N_CLS  50000
#define NVEC   (N_CLS / 4)      // 12500 float4 per row
#define PARTS  2
#define CHUNK  (NVEC / PARTS)   // 6250 float4 per block
#define NBLK   (D_ROWS * PARTS) // 2048

typedef float fx4 __attribute__((ext_vector_type(4)));

__global__ __launch_bounds__(256) void cluster_row_reduce(
    const float* __restrict__ W,
    float* __restrict__ sum_part,   // [NBLK]
    float* __restrict__ sq_part)    // [NBLK]
{
    const int b    = blockIdx.x;
    const int row  = b >> 1;
    const int part = b & 1;
    const fx4* __restrict__ Wp =
        reinterpret_cast<const fx4*>(W + (size_t)row * N_CLS) + part * CHUNK;

    float s = 0.0f, q = 0.0f;
    #pragma unroll 4
    for (int i = threadIdx.x; i < CHUNK; i += 256) {
        fx4 v = __builtin_nontemporal_load(&Wp[i]);
        s += (v.x + v.y) + (v.z + v.w);
        q += v.x * v.x + v.y * v.y + v.z * v.z + v.w * v.w;
    }

    #pragma unroll
    for (int off = 32; off; off >>= 1) {
        s += __shfl_down(s, off, 64);
        q += __shfl_down(q, off, 64);
    }

    __shared__ float ss[4], sq[4];
    const int wid  = threadIdx.x >> 6;
    const int lane = threadIdx.x & 63;
    if (lane == 0) { ss[wid] = s; sq[wid] = q; }
    __syncthreads();
    if (threadIdx.x == 0) {
        sum_part[b] = (ss[0] + ss[1]) + (ss[2] + ss[3]);
        sq_part[b]  = (sq[0] + sq[1]) + (sq[2] + sq[3]);
    }
}

__global__ __launch_bounds__(256) void cluster_final_reduce(
    const float* __restrict__ sum_part,
    const float* __restrict__ sq_part,
    const int* __restrict__ bs_ptr,
    float* __restrict__ out)
{
    // 2048 partials each; float4 loads -> 2 iters of 256 threads.
    const fx4* sp = reinterpret_cast<const fx4*>(sum_part);
    const fx4* qp = reinterpret_cast<const fx4*>(sq_part);

    float t2 = 0.0f, f = 0.0f;
    #pragma unroll
    for (int i = 0; i < NBLK / 4; i += 256) {
        fx4 vs = sp[i + threadIdx.x];
        fx4 vq = qp[i + threadIdx.x];
        float r0 = vs.x + vs.y;   // two parts of one row
        float r1 = vs.z + vs.w;   // two parts of next row
        t2 += r0 * r0 + r1 * r1;
        f  += (vq.x + vq.y) + (vq.z + vq.w);
    }

    #pragma unroll
    for (int off = 32; off; off >>= 1) {
        t2 += __shfl_down(t2, off, 64);
        f  += __shfl_down(f, off, 64);
    }

    __shared__ float st[4], sf[4];
    const int wid  = threadIdx.x >> 6;
    const int lane = threadIdx.x & 63;
    if (lane == 0) { st[wid] = t2; sf[wid] = f; }
    __syncthreads();
    if (threadIdx.x == 0) {
        float T2 = (st[0] + st[1]) + (st[2] + st[3]);
        float F  = (sf[0] + sf[1]) + (sf[2] + sf[3]);
        float bs = (float)bs_ptr[0];
        out[0] = F + 0.5f * (F - T2 / (float)N_CLS) / bs;
    }
}

extern "C" void kernel_launch(void* const* d_in, const int* in_sizes, int n_in,
                              void* d_out, int out_size, void* d_ws, size_t ws_size,
                              hipStream_t stream) {
    const float* W      = (const float*)d_in[0];
    // d_in[1] = group_ids : unused (loss is invariant to grouping — see header)
    const int*   bs_ptr = (const int*)d_in[2];
    float*       out    = (float*)d_out;

    float* sum_part = (float*)d_ws;          // NBLK floats
    float* sq_part  = sum_part + NBLK;       // NBLK floats

    cluster_row_reduce<<<NBLK, 256, 0, stream>>>(W, sum_part, sq_part);
    cluster_final_reduce<<<1, 256, 0, stream>>>(sum_part, sq_part, bs_ptr, out);
}